// Round 14
// baseline (151.493 us; speedup 1.0000x reference)
//
#include <hip/hip_runtime.h>
#include <hip/hip_bf16.h>
#include <stdint.h>

#define T_DIM 4096
#define H_DIM 1024
#define I_DIM 2048

typedef __bf16 bf16x8 __attribute__((ext_vector_type(8)));
typedef float f32x4 __attribute__((ext_vector_type(4)));
typedef unsigned short ushort_t;
typedef unsigned short us4 __attribute__((ext_vector_type(4)));

__device__ __forceinline__ unsigned short f32_to_bf16(float f) {
  unsigned int u = __float_as_uint(f);
  u += 0x7fffu + ((u >> 16) & 1u);  // RNE
  return (unsigned short)(u >> 16);
}

__device__ __forceinline__ void gload_lds16(const void* g, void* l) {
  __builtin_amdgcn_global_load_lds(
      (__attribute__((address_space(1))) void*)(uintptr_t)g,
      (__attribute__((address_space(3))) void*)(unsigned int)(uintptr_t)l,
      16, 0, 0);
}

// XOR swizzle (involution; bits 4-6 ^= bits 7-9 of byte offset). Verified R4:
// SQ_LDS_BANK_CONFLICT 6.29M -> 0. Transparent to adds of multiples of 1024.
__device__ __forceinline__ int swz(int L) { return L ^ (((L >> 7) & 7) << 4); }

#define S_BARRIER() asm volatile("s_barrier" ::: "memory")
#define WAITV(n) asm volatile("s_waitcnt vmcnt(" #n ")" ::: "memory")
#define IRFENCE() asm volatile("" ::: "memory")
#define MFMA16(acc, va, vb) \
  acc = __builtin_amdgcn_mfma_f32_16x16x32_bf16(va, vb, acc, 0, 0, 0)

// ------- transpose+convert body: src[R][C] f32 -> dst[C][R] bf16 ---------------
__device__ __forceinline__ void transpose_body(const float* __restrict__ src,
                                               ushort_t* __restrict__ dst,
                                               int R, int C, int bx, int by,
                                               int bz, float (*tile)[33]) {
  const size_t eoff = (size_t)bz * (size_t)R * (size_t)C;
  src += eoff;
  dst += eoff;
  const int x0 = bx * 32, y0 = by * 32;
  const int tx = threadIdx.x & 31, ty = threadIdx.x >> 5;
#pragma unroll
  for (int i = 0; i < 4; ++i)
    tile[ty + 8 * i][tx] = src[(size_t)(y0 + ty + 8 * i) * C + x0 + tx];
  __syncthreads();
#pragma unroll
  for (int i = 0; i < 4; ++i)
    dst[(size_t)(x0 + ty + 8 * i) * R + y0 + tx] = f32_to_bf16(tile[tx][ty + 8 * i]);
}

// ------- prep1: rmsnorm+out-init + w1 transpose + w2 transpose (one launch) ----
// blocks [0, T): rmsnorm row; [T, T+8192): tr1; [T+8192, T+12288): tr2.
__global__ __launch_bounds__(256) void k_prep1(
    const float* __restrict__ x, const float* __restrict__ scale,
    const float* __restrict__ b2, const float* __restrict__ w1,
    const float* __restrict__ w2, ushort_t* __restrict__ normed,
    float* __restrict__ out, ushort_t* __restrict__ w1T,
    ushort_t* __restrict__ w2T) {
  __shared__ __align__(16) float shm[32][33];
  const int bid = blockIdx.x;
  if (bid < T_DIM) {
    const int row = bid, tid = threadIdx.x;
    const float4 v = ((const float4*)(x + (size_t)row * H_DIM))[tid];
    float ss = v.x * v.x + v.y * v.y + v.z * v.z + v.w * v.w;
#pragma unroll
    for (int off = 32; off > 0; off >>= 1) ss += __shfl_xor(ss, off);
    if ((tid & 63) == 0) shm[0][tid >> 6] = ss;
    __syncthreads();
    const float tot = shm[0][0] + shm[0][1] + shm[0][2] + shm[0][3];
    const float inv = rsqrtf(tot * (1.0f / H_DIM) + 1e-5f);
    const float4 sc = ((const float4*)scale)[tid];
    us4 o;
    o.x = f32_to_bf16(v.x * inv * sc.x);
    o.y = f32_to_bf16(v.y * inv * sc.y);
    o.z = f32_to_bf16(v.z * inv * sc.z);
    o.w = f32_to_bf16(v.w * inv * sc.w);
    ((us4*)(normed + (size_t)row * H_DIM))[tid] = o;
    const float4 b0 = ((const float4*)b2)[tid];
    const float4 b1 = ((const float4*)(b2 + H_DIM))[tid];
    float4 ov;
    ov.x = v.x + 0.5f * (b0.x + b1.x);
    ov.y = v.y + 0.5f * (b0.y + b1.y);
    ov.z = v.z + 0.5f * (b0.z + b1.z);
    ov.w = v.w + 0.5f * (b0.w + b1.w);
    ((float4*)(out + (size_t)row * H_DIM))[tid] = ov;
  } else if (bid < T_DIM + 8192) {
    // w1 transpose: grid (2I/32=128, H/32=32, 2) flattened.
    const int t = bid - T_DIM;
    transpose_body(w1, w1T, H_DIM, 2 * I_DIM, t & 127, (t >> 7) & 31, t >> 12,
                   shm);
  } else {
    // w2 transpose: grid (H/32=32, I/32=64, 2) flattened.
    const int t = bid - T_DIM - 8192;
    transpose_body(w2, w2T, I_DIM, H_DIM, t & 31, (t >> 5) & 63, t >> 11,
                   shm);
  }
}

// ---------------- GEMM1 (R11-verified, 78.6us): 128 x (128g+128l), BK=32 -------
// Tri-buffer 72KB, 2 blocks/CU, 4 waves 2x2, wave 64x(64g+64l), WAITV(6)/step,
// stage 2 tiles ahead.
__global__ __launch_bounds__(256, 2) void k_gemm1(
    const ushort_t* __restrict__ normed, const ushort_t* __restrict__ w1T,
    const float* __restrict__ b1, ushort_t* __restrict__ act) {
  __shared__ __align__(16) ushort_t lds[3][3][4096];  // 72 KiB
  char* const ldsB = (char*)&lds[0][0][0];
  const int tid = threadIdx.x;
  const int wg = ((blockIdx.x & 7) << 7) + (blockIdx.x >> 3);  // XCD swizzle
  const int e = wg >> 9;
  const int rem = wg & 511;
  const int brow = (rem >> 4) * 128;
  const int bcol = (rem & 15) * 128;
  const int lane = tid & 63;
  const int wid = tid >> 6;
  const int wm = wid >> 1, wn = wid & 1;
  const int r16 = lane & 15, kh = lane >> 4;

  const ushort_t* gBase = w1T + ((size_t)e * 2 * I_DIM + bcol) * H_DIM;
  const ushort_t* lBase = w1T + ((size_t)e * 2 * I_DIM + I_DIM + bcol) * H_DIM;

  f32x4 accg[4][4], accl[4][4];
  const f32x4 zf = {0.f, 0.f, 0.f, 0.f};
#pragma unroll
  for (int m = 0; m < 4; ++m)
#pragma unroll
    for (int n = 0; n < 4; ++n) { accg[m][n] = zf; accl[m][n] = zf; }

  const ushort_t* pA[2];
  const ushort_t* pG[2];
  const ushort_t* pL[2];
#pragma unroll
  for (int j = 0; j < 2; ++j) {
    const int u = swz(j * 4096 + tid * 16);
    const int r = u >> 6, c = (u & 63) >> 1;
    pA[j] = normed + (size_t)(brow + r) * H_DIM + c;
    pG[j] = gBase + (size_t)r * H_DIM + c;
    pL[j] = lBase + (size_t)r * H_DIM + c;
  }
  const int ldst0 = (tid & ~63) * 16;

  const int abase = swz((wm * 64 + r16) * 64 + kh * 16);
  const int bbase = 8192 + swz((wn * 64 + r16) * 64 + kh * 16);

  auto stage = [&](int buf) {
#pragma unroll
    for (int j = 0; j < 2; ++j) {
      gload_lds16(pA[j], ldsB + buf * 24576 + j * 4096 + ldst0);
      gload_lds16(pG[j], ldsB + buf * 24576 + 8192 + j * 4096 + ldst0);
      gload_lds16(pL[j], ldsB + buf * 24576 + 16384 + j * 4096 + ldst0);
    }
  };

  bf16x8 a[4], bg[4], bl[4];

#define G1_ADV()                                                              \
  {                                                                           \
    _Pragma("unroll") for (int j = 0; j < 2; ++j) {                           \
      pA[j] += 32; pG[j] += 32; pL[j] += 32;                                  \
    }                                                                         \
  }
#define G1_RD(C)                                                              \
  _Pragma("unroll") for (int m = 0; m < 4; ++m)                               \
      a[m] = *(const bf16x8*)(ldsB + (C) * 24576 + abase + m * 1024);         \
  _Pragma("unroll") for (int n = 0; n < 4; ++n) {                             \
    bg[n] = *(const bf16x8*)(ldsB + (C) * 24576 + bbase + n * 1024);          \
    bl[n] = *(const bf16x8*)(ldsB + (C) * 24576 + bbase + 8192 + n * 1024);   \
  }
#define G1_MFMA()                                                             \
  _Pragma("unroll") for (int m = 0; m < 4; ++m)                               \
      _Pragma("unroll") for (int n = 0; n < 4; ++n) {                         \
    MFMA16(accg[m][n], a[m], bg[n]);                                          \
    MFMA16(accl[m][n], a[m], bl[n]);                                          \
  }
#define G1_STEP(C, N)                                                         \
  {                                                                           \
    G1_RD(C);                                                                 \
    stage(N);                                                                 \
    __builtin_amdgcn_s_setprio(1);                                            \
    G1_MFMA();                                                                \
    __builtin_amdgcn_s_setprio(0);                                            \
    WAITV(6);                                                                 \
    S_BARRIER();                                                              \
    G1_ADV();                                                                 \
  }

  stage(0); IRFENCE();
  G1_ADV();
  stage(1);
  G1_ADV();
  WAITV(6);
  S_BARRIER();

#pragma unroll 1
  for (int it = 0; it < 10; ++it) {  // steps t=0..29, staging t+2 (<=31)
    G1_STEP(0, 2);
    G1_STEP(1, 0);
    G1_STEP(2, 1);
  }
  // Tail: t=30 (b0; drained by step29's WAITV), t=31 (b1; in flight).
  {
    G1_RD(0);
    G1_MFMA();
    WAITV(0);
    S_BARRIER();
    G1_RD(1);
    G1_MFMA();
  }
#undef G1_STEP
#undef G1_MFMA
#undef G1_RD
#undef G1_ADV

  const float* b1e = b1 + (size_t)e * 2 * I_DIM;
#pragma unroll
  for (int m = 0; m < 4; ++m)
#pragma unroll
    for (int n = 0; n < 4; ++n) {
      const int gcol = bcol + wn * 64 + n * 16 + r16;
      const float bgb = b1e[gcol];
      const float blb = b1e[I_DIM + gcol];
#pragma unroll
      for (int rr = 0; rr < 4; ++rr) {
        const int grow = brow + wm * 64 + m * 16 + kh * 4 + rr;
        const float hg = accg[m][n][rr] + bgb;
        const float hl = accl[m][n][rr] + blb;
        const float g = fminf(hg, 7.f);
        const float l = fminf(fmaxf(hl, -7.f), 7.f);
        const float s = 1.f / (1.f + __expf(-1.702f * g));
        const float av = g * s * (l + 1.f);
        act[((size_t)e * T_DIM + grow) * I_DIM + gcol] = f32_to_bf16(av);
      }
    }
}

// ---------------- GEMM2 (R6-verified): 256x128, split-K=2 (expert) -------------
// 8 waves 4(wm)x2(wn), wave 64x64. Units per dbuf (24KB): A(256x32)=16KB +
// B(128x32)=8KB. 96 KiB LDS. 2 barriers/K-tile, WAITV(3) at each k-half
// boundary. Epilogue: atomicAdd 0.5*acc into out (pre-initialized x+bias).
__global__ __launch_bounds__(512, 2) void k_gemm2(
    const ushort_t* __restrict__ act, const ushort_t* __restrict__ w2T,
    float* __restrict__ out) {
  __shared__ __align__(16) ushort_t lds[2][2][12288];  // 96 KiB
  char* const ldsB = (char*)&lds[0][0][0];
  const int tid = threadIdx.x;
  const int wg = (blockIdx.x & 7) * 32 + (blockIdx.x >> 3);
  const int e = wg >> 7;
  const int tileid = wg & 127;
  const int brow = (tileid >> 3) * 256;
  const int bcol = (tileid & 7) * 128;
  const int lane = tid & 63;
  const int wm = (tid >> 6) >> 1;
  const int wn = (tid >> 6) & 1;
  const int r16 = lane & 15, kh = lane >> 4;

  const ushort_t* aBase = act + ((size_t)e * T_DIM + brow) * I_DIM;
  const ushort_t* bBase = w2T + ((size_t)e * H_DIM + bcol) * I_DIM;

  f32x4 acc[4][4];
  const f32x4 zf = {0.f, 0.f, 0.f, 0.f};
#pragma unroll
  for (int m = 0; m < 4; ++m)
#pragma unroll
    for (int n = 0; n < 4; ++n) acc[m][n] = zf;

  int srow[2], scolb[2];
#pragma unroll
  for (int j = 0; j < 2; ++j) {
    const int u = swz((j * 512 + tid) * 16);
    srow[j] = u >> 6;
    scolb[j] = (u & 63) >> 1;
  }
  const int ldst0 = (tid & ~63) * 16;

  const ushort_t* pA0 = aBase + (size_t)srow[0] * I_DIM + scolb[0];
  const ushort_t* pA1 = aBase + (size_t)srow[1] * I_DIM + scolb[1];
  const ushort_t* pB = bBase + (size_t)srow[0] * I_DIM + scolb[0];

  int aoffV[2][4], boffV[2][4];
#pragma unroll
  for (int bq = 0; bq < 2; ++bq) {
#pragma unroll
    for (int m = 0; m < 4; ++m)
      aoffV[bq][m] = bq * 49152 + swz((wm * 64 + m * 16 + r16) * 64 + kh * 16);
#pragma unroll
    for (int n = 0; n < 4; ++n)
      boffV[bq][n] = bq * 49152 + 16384 + swz((wn * 64 + n * 16 + r16) * 64 + kh * 16);
  }

  auto stageA = [&](int buf, int ksub) {
    gload_lds16(pA0 + ksub * 32, ldsB + buf * 49152 + ksub * 24576 + ldst0);
    gload_lds16(pA1 + ksub * 32, ldsB + buf * 49152 + ksub * 24576 + 8192 + ldst0);
  };
  auto stageB = [&](int buf, int ksub) {
    gload_lds16(pB + ksub * 32, ldsB + buf * 49152 + ksub * 24576 + 16384 + ldst0);
  };
  auto rdA = [&](int buf, int ksub, int m) -> bf16x8 {
    return *(const bf16x8*)(ldsB + aoffV[buf][m] + ksub * 24576);
  };
  auto rdB = [&](int buf, int ksub, int n) -> bf16x8 {
    return *(const bf16x8*)(ldsB + boffV[buf][n] + ksub * 24576);
  };

#define G2_ADV() \
  { pA0 += 64; pA1 += 64; pB += 64; }

#define G2_HALF(CUR, NXT, KS)                                                 \
  {                                                                           \
    _Pragma("unroll") for (int m = 0; m < 4; ++m) a[m] = rdA(CUR, KS, m);     \
    _Pragma("unroll") for (int n = 0; n < 4; ++n) b[n] = rdB(CUR, KS, n);     \
    stageA(NXT, KS);                                                          \
    stageB(NXT, KS);                                                          \
    __builtin_amdgcn_s_setprio(1);                                            \
    _Pragma("unroll") for (int m = 0; m < 4; ++m)                             \
        _Pragma("unroll") for (int n = 0; n < 4; ++n)                         \
            MFMA16(acc[m][n], a[m], b[n]);                                    \
    __builtin_amdgcn_s_setprio(0);                                            \
    WAITV(3);                                                                 \
    S_BARRIER();                                                              \
  }

#define G2_TILE(CUR, NXT)  \
  { G2_HALF(CUR, NXT, 0); G2_HALF(CUR, NXT, 1); G2_ADV(); }

  // Prologue.
  stageA(0, 0); stageB(0, 0); IRFENCE();
  stageA(0, 1); stageB(0, 1);
  G2_ADV();
  WAITV(3);
  S_BARRIER();

  bf16x8 a[4], b[4];
#pragma unroll 1
  for (int it = 0; it < 15; ++it) {  // tiles 0..29
    G2_TILE(0, 1);
    G2_TILE(1, 0);
  }
  G2_TILE(0, 1);  // tile 30, stages 31 into buf1

  // Tail: tile 31 in buf1.
  {
#pragma unroll
    for (int m = 0; m < 4; ++m) a[m] = rdA(1, 0, m);
#pragma unroll
    for (int n = 0; n < 4; ++n) b[n] = rdB(1, 0, n);
#pragma unroll
    for (int m = 0; m < 4; ++m)
#pragma unroll
      for (int n = 0; n < 4; ++n) MFMA16(acc[m][n], a[m], b[n]);
    WAITV(0);
    S_BARRIER();
#pragma unroll
    for (int m = 0; m < 4; ++m) a[m] = rdA(1, 1, m);
#pragma unroll
    for (int n = 0; n < 4; ++n) b[n] = rdB(1, 1, n);
#pragma unroll
    for (int m = 0; m < 4; ++m)
#pragma unroll
      for (int n = 0; n < 4; ++n) MFMA16(acc[m][n], a[m], b[n]);
  }
#undef G2_HALF
#undef G2_TILE
#undef G2_ADV

  // Epilogue: atomic accumulate 0.5*acc into out (pre-initialized x + bias).
#pragma unroll
  for (int m = 0; m < 4; ++m)
#pragma unroll
    for (int n = 0; n < 4; ++n) {
      const int gcol = bcol + wn * 64 + n * 16 + r16;
#pragma unroll
      for (int rr = 0; rr < 4; ++rr) {
        const int grow = brow + wm * 64 + m * 16 + kh * 4 + rr;
        atomicAdd(&out[(size_t)grow * H_DIM + gcol], 0.5f * acc[m][n][rr]);
      }
    }
}

extern "C" void kernel_launch(void* const* d_in, const int* in_sizes, int n_in,
                              void* d_out, int out_size, void* d_ws, size_t ws_size,
                              hipStream_t stream) {
  const float* x = (const float*)d_in[0];
  const float* scale = (const float*)d_in[1];
  // d_in[2]=gate_kernel, d_in[3]=gate_bias: static routing, logits unused.
  const float* w1 = (const float*)d_in[4];
  const float* b1 = (const float*)d_in[5];
  const float* w2 = (const float*)d_in[6];
  const float* b2 = (const float*)d_in[7];
  float* out = (float*)d_out;

  ushort_t* ws = (ushort_t*)d_ws;
  ushort_t* normed = ws;                                    // [T][H]
  ushort_t* w1T = normed + (size_t)T_DIM * H_DIM;           // [2][2I][H]
  ushort_t* w2T = w1T + (size_t)2 * 2 * I_DIM * H_DIM;      // [2][H][I]
  ushort_t* actb = w2T + (size_t)2 * H_DIM * I_DIM;         // [2][T][I]

  // prep1: rmsnorm+init (4096) + w1 transpose (8192) + w2 transpose (4096)
  k_prep1<<<dim3(T_DIM + 8192 + 4096), 256, 0, stream>>>(
      x, scale, b2, w1, w2, normed, out, w1T, w2T);
  k_gemm1<<<dim3(1024), 256, 0, stream>>>(normed, w1T, b1, actb);
  k_gemm2<<<dim3(256), 512, 0, stream>>>(actb, w2T, out);
}

// Round 15
// 149.391 us; speedup vs baseline: 1.0141x; 1.0141x over previous
//
#include <hip/hip_runtime.h>
#include <hip/hip_bf16.h>
#include <stdint.h>

#define T_DIM 4096
#define H_DIM 1024
#define I_DIM 2048

typedef __bf16 bf16x8 __attribute__((ext_vector_type(8)));
typedef float f32x4 __attribute__((ext_vector_type(4)));
typedef unsigned short ushort_t;
typedef unsigned short us4 __attribute__((ext_vector_type(4)));

__device__ __forceinline__ unsigned short f32_to_bf16(float f) {
  unsigned int u = __float_as_uint(f);
  u += 0x7fffu + ((u >> 16) & 1u);  // RNE
  return (unsigned short)(u >> 16);
}

__device__ __forceinline__ void gload_lds16(const void* g, void* l) {
  __builtin_amdgcn_global_load_lds(
      (__attribute__((address_space(1))) void*)(uintptr_t)g,
      (__attribute__((address_space(3))) void*)(unsigned int)(uintptr_t)l,
      16, 0, 0);
}

// XOR swizzle (involution; bits 4-6 ^= bits 7-9 of byte offset). Verified R4:
// SQ_LDS_BANK_CONFLICT 6.29M -> 0. Transparent to adds of multiples of 1024.
__device__ __forceinline__ int swz(int L) { return L ^ (((L >> 7) & 7) << 4); }

#define S_BARRIER() asm volatile("s_barrier" ::: "memory")
#define WAITV(n) asm volatile("s_waitcnt vmcnt(" #n ")" ::: "memory")
#define IRFENCE() asm volatile("" ::: "memory")
#define MFMA16(acc, va, vb) \
  acc = __builtin_amdgcn_mfma_f32_16x16x32_bf16(va, vb, acc, 0, 0, 0)

// ------- 64x64 vectorized transpose+convert: src[R][C] f32 -> dst[C][R] bf16 ---
// Loads float4/lane (16B), stores us4/lane (8B, 128B per 16-lane group).
// LDS [64][65]: load phase 2-way bank alias, store phase 2-way — both free.
__device__ __forceinline__ void transpose_body64(const float* __restrict__ src,
                                                 ushort_t* __restrict__ dst,
                                                 int R, int C, int bx, int by,
                                                 int bz, float (*tile)[65]) {
  const size_t eoff = (size_t)bz * (size_t)R * (size_t)C;
  src += eoff;
  dst += eoff;
  const int x0 = bx * 64, y0 = by * 64;
  const int tid = threadIdx.x;
  const int lcol4 = tid & 15, lrow = tid >> 4;  // 16 float4-cols x 16 rows
#pragma unroll
  for (int i = 0; i < 4; ++i) {
    const int r = lrow + 16 * i;
    const float4 v =
        ((const float4*)(src + (size_t)(y0 + r) * C + x0))[lcol4];
    tile[r][lcol4 * 4 + 0] = v.x;
    tile[r][lcol4 * 4 + 1] = v.y;
    tile[r][lcol4 * 4 + 2] = v.z;
    tile[r][lcol4 * 4 + 3] = v.w;
  }
  __syncthreads();
  const int slotr = tid & 15, lcol = tid >> 4;  // 16 row-quads x 16 cols
#pragma unroll
  for (int i = 0; i < 4; ++i) {
    const int c = lcol + 16 * i;
    us4 o;
    o.x = f32_to_bf16(tile[slotr * 4 + 0][c]);
    o.y = f32_to_bf16(tile[slotr * 4 + 1][c]);
    o.z = f32_to_bf16(tile[slotr * 4 + 2][c]);
    o.w = f32_to_bf16(tile[slotr * 4 + 3][c]);
    *(us4*)(dst + (size_t)(x0 + c) * R + y0 + slotr * 4) = o;
  }
}

// ------- prep1: rmsnorm+out-init + w1 transpose + w2 transpose (one launch) ----
// blocks [0, T): rmsnorm row; [T, T+2048): tr1 (64x64); [T+2048, T+3072): tr2.
__global__ __launch_bounds__(256) void k_prep1(
    const float* __restrict__ x, const float* __restrict__ scale,
    const float* __restrict__ b2, const float* __restrict__ w1,
    const float* __restrict__ w2, ushort_t* __restrict__ normed,
    float* __restrict__ out, ushort_t* __restrict__ w1T,
    ushort_t* __restrict__ w2T) {
  __shared__ __align__(16) float shm[64][65];
  const int bid = blockIdx.x;
  if (bid < T_DIM) {
    const int row = bid, tid = threadIdx.x;
    const float4 v = ((const float4*)(x + (size_t)row * H_DIM))[tid];
    float ss = v.x * v.x + v.y * v.y + v.z * v.z + v.w * v.w;
#pragma unroll
    for (int off = 32; off > 0; off >>= 1) ss += __shfl_xor(ss, off);
    if ((tid & 63) == 0) shm[0][tid >> 6] = ss;
    __syncthreads();
    const float tot = shm[0][0] + shm[0][1] + shm[0][2] + shm[0][3];
    const float inv = rsqrtf(tot * (1.0f / H_DIM) + 1e-5f);
    const float4 sc = ((const float4*)scale)[tid];
    us4 o;
    o.x = f32_to_bf16(v.x * inv * sc.x);
    o.y = f32_to_bf16(v.y * inv * sc.y);
    o.z = f32_to_bf16(v.z * inv * sc.z);
    o.w = f32_to_bf16(v.w * inv * sc.w);
    ((us4*)(normed + (size_t)row * H_DIM))[tid] = o;
    const float4 b0 = ((const float4*)b2)[tid];
    const float4 b1 = ((const float4*)(b2 + H_DIM))[tid];
    float4 ov;
    ov.x = v.x + 0.5f * (b0.x + b1.x);
    ov.y = v.y + 0.5f * (b0.y + b1.y);
    ov.z = v.z + 0.5f * (b0.z + b1.z);
    ov.w = v.w + 0.5f * (b0.w + b1.w);
    ((float4*)(out + (size_t)row * H_DIM))[tid] = ov;
  } else if (bid < T_DIM + 2048) {
    // w1 transpose: [H][2I] -> [2I][H]; grid (2I/64=64, H/64=16, 2) flattened.
    const int t = bid - T_DIM;
    transpose_body64(w1, w1T, H_DIM, 2 * I_DIM, t & 63, (t >> 6) & 15, t >> 10,
                     shm);
  } else {
    // w2 transpose: [I][H] -> [H][I]; grid (H/64=16, I/64=32, 2) flattened.
    const int t = bid - T_DIM - 2048;
    transpose_body64(w2, w2T, I_DIM, H_DIM, t & 15, (t >> 4) & 31, t >> 9,
                     shm);
  }
}

// ---------------- GEMM1 (R11-verified, 78.6us): 128 x (128g+128l), BK=32 -------
// Tri-buffer 72KB, 2 blocks/CU, 4 waves 2x2, wave 64x(64g+64l), WAITV(6)/step,
// stage 2 tiles ahead.
__global__ __launch_bounds__(256, 2) void k_gemm1(
    const ushort_t* __restrict__ normed, const ushort_t* __restrict__ w1T,
    const float* __restrict__ b1, ushort_t* __restrict__ act) {
  __shared__ __align__(16) ushort_t lds[3][3][4096];  // 72 KiB
  char* const ldsB = (char*)&lds[0][0][0];
  const int tid = threadIdx.x;
  const int wg = ((blockIdx.x & 7) << 7) + (blockIdx.x >> 3);  // XCD swizzle
  const int e = wg >> 9;
  const int rem = wg & 511;
  const int brow = (rem >> 4) * 128;
  const int bcol = (rem & 15) * 128;
  const int lane = tid & 63;
  const int wid = tid >> 6;
  const int wm = wid >> 1, wn = wid & 1;
  const int r16 = lane & 15, kh = lane >> 4;

  const ushort_t* gBase = w1T + ((size_t)e * 2 * I_DIM + bcol) * H_DIM;
  const ushort_t* lBase = w1T + ((size_t)e * 2 * I_DIM + I_DIM + bcol) * H_DIM;

  f32x4 accg[4][4], accl[4][4];
  const f32x4 zf = {0.f, 0.f, 0.f, 0.f};
#pragma unroll
  for (int m = 0; m < 4; ++m)
#pragma unroll
    for (int n = 0; n < 4; ++n) { accg[m][n] = zf; accl[m][n] = zf; }

  const ushort_t* pA[2];
  const ushort_t* pG[2];
  const ushort_t* pL[2];
#pragma unroll
  for (int j = 0; j < 2; ++j) {
    const int u = swz(j * 4096 + tid * 16);
    const int r = u >> 6, c = (u & 63) >> 1;
    pA[j] = normed + (size_t)(brow + r) * H_DIM + c;
    pG[j] = gBase + (size_t)r * H_DIM + c;
    pL[j] = lBase + (size_t)r * H_DIM + c;
  }
  const int ldst0 = (tid & ~63) * 16;

  const int abase = swz((wm * 64 + r16) * 64 + kh * 16);
  const int bbase = 8192 + swz((wn * 64 + r16) * 64 + kh * 16);

  auto stage = [&](int buf) {
#pragma unroll
    for (int j = 0; j < 2; ++j) {
      gload_lds16(pA[j], ldsB + buf * 24576 + j * 4096 + ldst0);
      gload_lds16(pG[j], ldsB + buf * 24576 + 8192 + j * 4096 + ldst0);
      gload_lds16(pL[j], ldsB + buf * 24576 + 16384 + j * 4096 + ldst0);
    }
  };

  bf16x8 a[4], bg[4], bl[4];

#define G1_ADV()                                                              \
  {                                                                           \
    _Pragma("unroll") for (int j = 0; j < 2; ++j) {                           \
      pA[j] += 32; pG[j] += 32; pL[j] += 32;                                  \
    }                                                                         \
  }
#define G1_RD(C)                                                              \
  _Pragma("unroll") for (int m = 0; m < 4; ++m)                               \
      a[m] = *(const bf16x8*)(ldsB + (C) * 24576 + abase + m * 1024);         \
  _Pragma("unroll") for (int n = 0; n < 4; ++n) {                             \
    bg[n] = *(const bf16x8*)(ldsB + (C) * 24576 + bbase + n * 1024);          \
    bl[n] = *(const bf16x8*)(ldsB + (C) * 24576 + bbase + 8192 + n * 1024);   \
  }
#define G1_MFMA()                                                             \
  _Pragma("unroll") for (int m = 0; m < 4; ++m)                               \
      _Pragma("unroll") for (int n = 0; n < 4; ++n) {                         \
    MFMA16(accg[m][n], a[m], bg[n]);                                          \
    MFMA16(accl[m][n], a[m], bl[n]);                                          \
  }
#define G1_STEP(C, N)                                                         \
  {                                                                           \
    G1_RD(C);                                                                 \
    stage(N);                                                                 \
    __builtin_amdgcn_s_setprio(1);                                            \
    G1_MFMA();                                                                \
    __builtin_amdgcn_s_setprio(0);                                            \
    WAITV(6);                                                                 \
    S_BARRIER();                                                              \
    G1_ADV();                                                                 \
  }

  stage(0); IRFENCE();
  G1_ADV();
  stage(1);
  G1_ADV();
  WAITV(6);
  S_BARRIER();

#pragma unroll 1
  for (int it = 0; it < 10; ++it) {  // steps t=0..29, staging t+2 (<=31)
    G1_STEP(0, 2);
    G1_STEP(1, 0);
    G1_STEP(2, 1);
  }
  // Tail: t=30 (b0; drained by step29's WAITV), t=31 (b1; in flight).
  {
    G1_RD(0);
    G1_MFMA();
    WAITV(0);
    S_BARRIER();
    G1_RD(1);
    G1_MFMA();
  }
#undef G1_STEP
#undef G1_MFMA
#undef G1_RD
#undef G1_ADV

  const float* b1e = b1 + (size_t)e * 2 * I_DIM;
#pragma unroll
  for (int m = 0; m < 4; ++m)
#pragma unroll
    for (int n = 0; n < 4; ++n) {
      const int gcol = bcol + wn * 64 + n * 16 + r16;
      const float bgb = b1e[gcol];
      const float blb = b1e[I_DIM + gcol];
#pragma unroll
      for (int rr = 0; rr < 4; ++rr) {
        const int grow = brow + wm * 64 + m * 16 + kh * 4 + rr;
        const float hg = accg[m][n][rr] + bgb;
        const float hl = accl[m][n][rr] + blb;
        const float g = fminf(hg, 7.f);
        const float l = fminf(fmaxf(hl, -7.f), 7.f);
        const float s = 1.f / (1.f + __expf(-1.702f * g));
        const float av = g * s * (l + 1.f);
        act[((size_t)e * T_DIM + grow) * I_DIM + gcol] = f32_to_bf16(av);
      }
    }
}

// ---------------- GEMM2 (R6-verified): 256x128, split-K=2 (expert) -------------
__global__ __launch_bounds__(512, 2) void k_gemm2(
    const ushort_t* __restrict__ act, const ushort_t* __restrict__ w2T,
    float* __restrict__ out) {
  __shared__ __align__(16) ushort_t lds[2][2][12288];  // 96 KiB
  char* const ldsB = (char*)&lds[0][0][0];
  const int tid = threadIdx.x;
  const int wg = (blockIdx.x & 7) * 32 + (blockIdx.x >> 3);
  const int e = wg >> 7;
  const int tileid = wg & 127;
  const int brow = (tileid >> 3) * 256;
  const int bcol = (tileid & 7) * 128;
  const int lane = tid & 63;
  const int wm = (tid >> 6) >> 1;
  const int wn = (tid >> 6) & 1;
  const int r16 = lane & 15, kh = lane >> 4;

  const ushort_t* aBase = act + ((size_t)e * T_DIM + brow) * I_DIM;
  const ushort_t* bBase = w2T + ((size_t)e * H_DIM + bcol) * I_DIM;

  f32x4 acc[4][4];
  const f32x4 zf = {0.f, 0.f, 0.f, 0.f};
#pragma unroll
  for (int m = 0; m < 4; ++m)
#pragma unroll
    for (int n = 0; n < 4; ++n) acc[m][n] = zf;

  int srow[2], scolb[2];
#pragma unroll
  for (int j = 0; j < 2; ++j) {
    const int u = swz((j * 512 + tid) * 16);
    srow[j] = u >> 6;
    scolb[j] = (u & 63) >> 1;
  }
  const int ldst0 = (tid & ~63) * 16;

  const ushort_t* pA0 = aBase + (size_t)srow[0] * I_DIM + scolb[0];
  const ushort_t* pA1 = aBase + (size_t)srow[1] * I_DIM + scolb[1];
  const ushort_t* pB = bBase + (size_t)srow[0] * I_DIM + scolb[0];

  int aoffV[2][4], boffV[2][4];
#pragma unroll
  for (int bq = 0; bq < 2; ++bq) {
#pragma unroll
    for (int m = 0; m < 4; ++m)
      aoffV[bq][m] = bq * 49152 + swz((wm * 64 + m * 16 + r16) * 64 + kh * 16);
#pragma unroll
    for (int n = 0; n < 4; ++n)
      boffV[bq][n] = bq * 49152 + 16384 + swz((wn * 64 + n * 16 + r16) * 64 + kh * 16);
  }

  auto stageA = [&](int buf, int ksub) {
    gload_lds16(pA0 + ksub * 32, ldsB + buf * 49152 + ksub * 24576 + ldst0);
    gload_lds16(pA1 + ksub * 32, ldsB + buf * 49152 + ksub * 24576 + 8192 + ldst0);
  };
  auto stageB = [&](int buf, int ksub) {
    gload_lds16(pB + ksub * 32, ldsB + buf * 49152 + ksub * 24576 + 16384 + ldst0);
  };
  auto rdA = [&](int buf, int ksub, int m) -> bf16x8 {
    return *(const bf16x8*)(ldsB + aoffV[buf][m] + ksub * 24576);
  };
  auto rdB = [&](int buf, int ksub, int n) -> bf16x8 {
    return *(const bf16x8*)(ldsB + boffV[buf][n] + ksub * 24576);
  };

#define G2_ADV() \
  { pA0 += 64; pA1 += 64; pB += 64; }

#define G2_HALF(CUR, NXT, KS)                                                 \
  {                                                                           \
    _Pragma("unroll") for (int m = 0; m < 4; ++m) a[m] = rdA(CUR, KS, m);     \
    _Pragma("unroll") for (int n = 0; n < 4; ++n) b[n] = rdB(CUR, KS, n);     \
    stageA(NXT, KS);                                                          \
    stageB(NXT, KS);                                                          \
    __builtin_amdgcn_s_setprio(1);                                            \
    _Pragma("unroll") for (int m = 0; m < 4; ++m)                             \
        _Pragma("unroll") for (int n = 0; n < 4; ++n)                         \
            MFMA16(acc[m][n], a[m], b[n]);                                    \
    __builtin_amdgcn_s_setprio(0);                                            \
    WAITV(3);                                                                 \
    S_BARRIER();                                                              \
  }

#define G2_TILE(CUR, NXT)  \
  { G2_HALF(CUR, NXT, 0); G2_HALF(CUR, NXT, 1); G2_ADV(); }

  // Prologue.
  stageA(0, 0); stageB(0, 0); IRFENCE();
  stageA(0, 1); stageB(0, 1);
  G2_ADV();
  WAITV(3);
  S_BARRIER();

  bf16x8 a[4], b[4];
#pragma unroll 1
  for (int it = 0; it < 15; ++it) {  // tiles 0..29
    G2_TILE(0, 1);
    G2_TILE(1, 0);
  }
  G2_TILE(0, 1);  // tile 30, stages 31 into buf1

  // Tail: tile 31 in buf1.
  {
#pragma unroll
    for (int m = 0; m < 4; ++m) a[m] = rdA(1, 0, m);
#pragma unroll
    for (int n = 0; n < 4; ++n) b[n] = rdB(1, 0, n);
#pragma unroll
    for (int m = 0; m < 4; ++m)
#pragma unroll
      for (int n = 0; n < 4; ++n) MFMA16(acc[m][n], a[m], b[n]);
    WAITV(0);
    S_BARRIER();
#pragma unroll
    for (int m = 0; m < 4; ++m) a[m] = rdA(1, 1, m);
#pragma unroll
    for (int n = 0; n < 4; ++n) b[n] = rdB(1, 1, n);
#pragma unroll
    for (int m = 0; m < 4; ++m)
#pragma unroll
      for (int n = 0; n < 4; ++n) MFMA16(acc[m][n], a[m], b[n]);
  }
#undef G2_HALF
#undef G2_TILE
#undef G2_ADV

  // Epilogue: atomic accumulate 0.5*acc into out (pre-initialized x + bias).
#pragma unroll
  for (int m = 0; m < 4; ++m)
#pragma unroll
    for (int n = 0; n < 4; ++n) {
      const int gcol = bcol + wn * 64 + n * 16 + r16;
#pragma unroll
      for (int rr = 0; rr < 4; ++rr) {
        const int grow = brow + wm * 64 + m * 16 + kh * 4 + rr;
        atomicAdd(&out[(size_t)grow * H_DIM + gcol], 0.5f * acc[m][n][rr]);
      }
    }
}

extern "C" void kernel_launch(void* const* d_in, const int* in_sizes, int n_in,
                              void* d_out, int out_size, void* d_ws, size_t ws_size,
                              hipStream_t stream) {
  const float* x = (const float*)d_in[0];
  const float* scale = (const float*)d_in[1];
  // d_in[2]=gate_kernel, d_in[3]=gate_bias: static routing, logits unused.
  const float* w1 = (const float*)d_in[4];
  const float* b1 = (const float*)d_in[5];
  const float* w2 = (const float*)d_in[6];
  const float* b2 = (const float*)d_in[7];
  float* out = (float*)d_out;

  ushort_t* ws = (ushort_t*)d_ws;
  ushort_t* normed = ws;                                    // [T][H]
  ushort_t* w1T = normed + (size_t)T_DIM * H_DIM;           // [2][2I][H]
  ushort_t* w2T = w1T + (size_t)2 * 2 * I_DIM * H_DIM;      // [2][H][I]
  ushort_t* actb = w2T + (size_t)2 * H_DIM * I_DIM;         // [2][T][I]

  // prep1: rmsnorm+init (4096) + w1 transpose 64x64 (2048) + w2 transpose (1024)
  k_prep1<<<dim3(T_DIM + 2048 + 1024), 256, 0, stream>>>(
      x, scale, b2, w1, w2, normed, out, w1T, w2T);
  k_gemm1<<<dim3(1024), 256, 0, stream>>>(normed, w1T, b1, actb);
  k_gemm2<<<dim3(256), 512, 0, stream>>>(actb, w2T, out);
}

// Round 16
// 148.294 us; speedup vs baseline: 1.0216x; 1.0074x over previous
//
#include <hip/hip_runtime.h>
#include <hip/hip_bf16.h>
#include <stdint.h>

#define T_DIM 4096
#define H_DIM 1024
#define I_DIM 2048
#define KCAT 4096  // concatenated K for gemm2 (2 experts x I_DIM)

typedef __bf16 bf16x8 __attribute__((ext_vector_type(8)));
typedef float f32x4 __attribute__((ext_vector_type(4)));
typedef unsigned short ushort_t;
typedef unsigned short us4 __attribute__((ext_vector_type(4)));
typedef unsigned short us8 __attribute__((ext_vector_type(8)));

__device__ __forceinline__ unsigned short f32_to_bf16(float f) {
  unsigned int u = __float_as_uint(f);
  u += 0x7fffu + ((u >> 16) & 1u);  // RNE
  return (unsigned short)(u >> 16);
}

__device__ __forceinline__ void gload_lds16(const void* g, void* l) {
  __builtin_amdgcn_global_load_lds(
      (__attribute__((address_space(1))) void*)(uintptr_t)g,
      (__attribute__((address_space(3))) void*)(unsigned int)(uintptr_t)l,
      16, 0, 0);
}

// XOR swizzle (involution; bits 4-6 ^= bits 7-9 of byte offset). Verified R4:
// SQ_LDS_BANK_CONFLICT 6.29M -> 0. Transparent to adds of multiples of 1024.
__device__ __forceinline__ int swz(int L) { return L ^ (((L >> 7) & 7) << 4); }

#define S_BARRIER() asm volatile("s_barrier" ::: "memory")
#define WAITV(n) asm volatile("s_waitcnt vmcnt(" #n ")" ::: "memory")
#define IRFENCE() asm volatile("" ::: "memory")
#define MFMA16(acc, va, vb) \
  acc = __builtin_amdgcn_mfma_f32_16x16x32_bf16(va, vb, acc, 0, 0, 0)

// ------- 64x64 transpose+convert: src f32 (stride sC) -> dst bf16 (stride dR) --
// Loads float4/lane; stores us8/lane (16B). LDS reads 2-way bank alias = free.
__device__ __forceinline__ void transpose_body64(const float* __restrict__ src,
                                                 ushort_t* __restrict__ dst,
                                                 int sC, int dR, int bx, int by,
                                                 float (*tile)[65]) {
  const int x0 = bx * 64, y0 = by * 64;
  const int tid = threadIdx.x;
  const int lcol4 = tid & 15, lrow = tid >> 4;
#pragma unroll
  for (int i = 0; i < 4; ++i) {
    const int r = lrow + 16 * i;
    const float4 v = ((const float4*)(src + (size_t)(y0 + r) * sC + x0))[lcol4];
    tile[r][lcol4 * 4 + 0] = v.x;
    tile[r][lcol4 * 4 + 1] = v.y;
    tile[r][lcol4 * 4 + 2] = v.z;
    tile[r][lcol4 * 4 + 3] = v.w;
  }
  __syncthreads();
  const int slotr = tid & 7, lcol = tid >> 3;  // 8 row-octs x 32 cols
#pragma unroll
  for (int i = 0; i < 2; ++i) {
    const int c = lcol + 32 * i;
    us8 o;
#pragma unroll
    for (int j = 0; j < 8; ++j) o[j] = f32_to_bf16(tile[slotr * 8 + j][c]);
    *(us8*)(dst + (size_t)(x0 + c) * dR + y0 + slotr * 8) = o;
  }
}

// ------- prep1: rmsnorm (blocks 0..T) + w1T (next 2048) + w2c (next 1024) ------
__global__ __launch_bounds__(256) void k_prep1(
    const float* __restrict__ x, const float* __restrict__ scale,
    const float* __restrict__ w1, const float* __restrict__ w2,
    ushort_t* __restrict__ normed, ushort_t* __restrict__ w1T,
    ushort_t* __restrict__ w2c) {
  __shared__ __align__(16) float shm[64][65];
  const int bid = blockIdx.x;
  if (bid < T_DIM) {
    const int row = bid, tid = threadIdx.x;
    const float4 v = ((const float4*)(x + (size_t)row * H_DIM))[tid];
    float ss = v.x * v.x + v.y * v.y + v.z * v.z + v.w * v.w;
#pragma unroll
    for (int off = 32; off > 0; off >>= 1) ss += __shfl_xor(ss, off);
    if ((tid & 63) == 0) shm[0][tid >> 6] = ss;
    __syncthreads();
    const float tot = shm[0][0] + shm[0][1] + shm[0][2] + shm[0][3];
    const float inv = rsqrtf(tot * (1.0f / H_DIM) + 1e-5f);
    const float4 sc = ((const float4*)scale)[tid];
    us4 o;
    o.x = f32_to_bf16(v.x * inv * sc.x);
    o.y = f32_to_bf16(v.y * inv * sc.y);
    o.z = f32_to_bf16(v.z * inv * sc.z);
    o.w = f32_to_bf16(v.w * inv * sc.w);
    ((us4*)(normed + (size_t)row * H_DIM))[tid] = o;
  } else if (bid < T_DIM + 2048) {
    // w1 [H][2I] -> w1T [2][2I][H]; grid (2I/64=64, H/64=16, 2) flattened.
    const int t = bid - T_DIM;
    const int e = t >> 10;
    transpose_body64(w1 + (size_t)e * H_DIM * 2 * I_DIM,
                     w1T + (size_t)e * 2 * I_DIM * H_DIM, 2 * I_DIM, H_DIM,
                     t & 63, (t >> 6) & 15, shm);
  } else {
    // w2 [I][H] -> w2c [H][KCAT] (expert e at col offset e*I);
    // grid (H/64=16, I/64=32, 2) flattened.
    const int t = bid - T_DIM - 2048;
    const int e = t >> 9;
    transpose_body64(w2 + (size_t)e * I_DIM * H_DIM, w2c + (size_t)e * I_DIM,
                     H_DIM, KCAT, t & 15, (t >> 4) & 31, shm);
  }
}

// ---------------- GEMM1 (R11-verified): 128 x (128g+128l), BK=32 ---------------
// Tri-buffer 72KB, 2 blocks/CU, 4 waves 2x2, WAITV(6)/step, stage 2 ahead.
// Epilogue writes act in the [T][KCAT] expert-concat layout.
__global__ __launch_bounds__(256, 2) void k_gemm1(
    const ushort_t* __restrict__ normed, const ushort_t* __restrict__ w1T,
    const float* __restrict__ b1, ushort_t* __restrict__ act) {
  __shared__ __align__(16) ushort_t lds[3][3][4096];  // 72 KiB
  char* const ldsB = (char*)&lds[0][0][0];
  const int tid = threadIdx.x;
  const int wg = ((blockIdx.x & 7) << 7) + (blockIdx.x >> 3);  // XCD swizzle
  const int e = wg >> 9;
  const int rem = wg & 511;
  const int brow = (rem >> 4) * 128;
  const int bcol = (rem & 15) * 128;
  const int lane = tid & 63;
  const int wid = tid >> 6;
  const int wm = wid >> 1, wn = wid & 1;
  const int r16 = lane & 15, kh = lane >> 4;

  const ushort_t* gBase = w1T + ((size_t)e * 2 * I_DIM + bcol) * H_DIM;
  const ushort_t* lBase = w1T + ((size_t)e * 2 * I_DIM + I_DIM + bcol) * H_DIM;

  f32x4 accg[4][4], accl[4][4];
  const f32x4 zf = {0.f, 0.f, 0.f, 0.f};
#pragma unroll
  for (int m = 0; m < 4; ++m)
#pragma unroll
    for (int n = 0; n < 4; ++n) { accg[m][n] = zf; accl[m][n] = zf; }

  const ushort_t* pA[2];
  const ushort_t* pG[2];
  const ushort_t* pL[2];
#pragma unroll
  for (int j = 0; j < 2; ++j) {
    const int u = swz(j * 4096 + tid * 16);
    const int r = u >> 6, c = (u & 63) >> 1;
    pA[j] = normed + (size_t)(brow + r) * H_DIM + c;
    pG[j] = gBase + (size_t)r * H_DIM + c;
    pL[j] = lBase + (size_t)r * H_DIM + c;
  }
  const int ldst0 = (tid & ~63) * 16;

  const int abase = swz((wm * 64 + r16) * 64 + kh * 16);
  const int bbase = 8192 + swz((wn * 64 + r16) * 64 + kh * 16);

  auto stage = [&](int buf) {
#pragma unroll
    for (int j = 0; j < 2; ++j) {
      gload_lds16(pA[j], ldsB + buf * 24576 + j * 4096 + ldst0);
      gload_lds16(pG[j], ldsB + buf * 24576 + 8192 + j * 4096 + ldst0);
      gload_lds16(pL[j], ldsB + buf * 24576 + 16384 + j * 4096 + ldst0);
    }
  };

  bf16x8 a[4], bg[4], bl[4];

#define G1_ADV()                                                              \
  {                                                                           \
    _Pragma("unroll") for (int j = 0; j < 2; ++j) {                           \
      pA[j] += 32; pG[j] += 32; pL[j] += 32;                                  \
    }                                                                         \
  }
#define G1_RD(C)                                                              \
  _Pragma("unroll") for (int m = 0; m < 4; ++m)                               \
      a[m] = *(const bf16x8*)(ldsB + (C) * 24576 + abase + m * 1024);         \
  _Pragma("unroll") for (int n = 0; n < 4; ++n) {                             \
    bg[n] = *(const bf16x8*)(ldsB + (C) * 24576 + bbase + n * 1024);          \
    bl[n] = *(const bf16x8*)(ldsB + (C) * 24576 + bbase + 8192 + n * 1024);   \
  }
#define G1_MFMA()                                                             \
  _Pragma("unroll") for (int m = 0; m < 4; ++m)                               \
      _Pragma("unroll") for (int n = 0; n < 4; ++n) {                         \
    MFMA16(accg[m][n], a[m], bg[n]);                                          \
    MFMA16(accl[m][n], a[m], bl[n]);                                          \
  }
#define G1_STEP(C, N)                                                         \
  {                                                                           \
    G1_RD(C);                                                                 \
    stage(N);                                                                 \
    __builtin_amdgcn_s_setprio(1);                                            \
    G1_MFMA();                                                                \
    __builtin_amdgcn_s_setprio(0);                                            \
    WAITV(6);                                                                 \
    S_BARRIER();                                                              \
    G1_ADV();                                                                 \
  }

  stage(0); IRFENCE();
  G1_ADV();
  stage(1);
  G1_ADV();
  WAITV(6);
  S_BARRIER();

#pragma unroll 1
  for (int it = 0; it < 10; ++it) {  // steps t=0..29, staging t+2 (<=31)
    G1_STEP(0, 2);
    G1_STEP(1, 0);
    G1_STEP(2, 1);
  }
  // Tail: t=30 (b0; drained by step29's WAITV), t=31 (b1; in flight).
  {
    G1_RD(0);
    G1_MFMA();
    WAITV(0);
    S_BARRIER();
    G1_RD(1);
    G1_MFMA();
  }
#undef G1_STEP
#undef G1_MFMA
#undef G1_RD
#undef G1_ADV

  const float* b1e = b1 + (size_t)e * 2 * I_DIM;
#pragma unroll
  for (int m = 0; m < 4; ++m)
#pragma unroll
    for (int n = 0; n < 4; ++n) {
      const int gcol = bcol + wn * 64 + n * 16 + r16;
      const float bgb = b1e[gcol];
      const float blb = b1e[I_DIM + gcol];
#pragma unroll
      for (int rr = 0; rr < 4; ++rr) {
        const int grow = brow + wm * 64 + m * 16 + kh * 4 + rr;
        const float hg = accg[m][n][rr] + bgb;
        const float hl = accl[m][n][rr] + blb;
        const float g = fminf(hg, 7.f);
        const float l = fminf(fmaxf(hl, -7.f), 7.f);
        const float s = 1.f / (1.f + __expf(-1.702f * g));
        const float av = g * s * (l + 1.f);
        act[(size_t)grow * KCAT + e * I_DIM + gcol] = f32_to_bf16(av);
      }
    }
}

// ---------------- GEMM2: plain GEMM, K=4096 concat, no atomics -----------------
// out[T][H] = x + 0.5*(act[T][KCAT] @ w2c[H][KCAT]^T) + 0.5*(b2[0]+b2[1]).
// 128x64 tiles, grid 512, 3 blocks/CU (36KB tri-buffer), 4 waves 2x2
// (wave 64x32), R11's verified ring: 3 loads/stage, WAITV(3)/step, stage 2
// ahead, 128 K-steps = 42x3 + 2 tail.
__global__ __launch_bounds__(256, 3) void k_gemm2(
    const ushort_t* __restrict__ act, const ushort_t* __restrict__ w2c,
    const float* __restrict__ x, const float* __restrict__ b2,
    float* __restrict__ out) {
  __shared__ __align__(16) ushort_t lds[3][6144];  // 36 KiB: per buf A 8K + B 4K
  char* const ldsB = (char*)&lds[0][0];
  const int tid = threadIdx.x;
  const int wg = ((blockIdx.x & 7) << 6) + (blockIdx.x >> 3);  // XCD swizzle
  const int brow = (wg >> 4) * 128;  // 32 rowtiles
  const int bcol = (wg & 15) * 64;   // 16 coltiles
  const int lane = tid & 63;
  const int wid = tid >> 6;
  const int wm = wid >> 1, wn = wid & 1;
  const int r16 = lane & 15, kh = lane >> 4;

  const ushort_t* aBase = act + (size_t)brow * KCAT;
  const ushort_t* bBase = w2c + (size_t)bcol * KCAT;

  f32x4 acc[4][2];
  const f32x4 zf = {0.f, 0.f, 0.f, 0.f};
#pragma unroll
  for (int m = 0; m < 4; ++m)
#pragma unroll
    for (int n = 0; n < 2; ++n) acc[m][n] = zf;

  const ushort_t* pA[2];
  const ushort_t* pB;
  {
#pragma unroll
    for (int j = 0; j < 2; ++j) {
      const int u = swz(j * 4096 + tid * 16);
      pA[j] = aBase + (size_t)(u >> 6) * KCAT + ((u & 63) >> 1);
    }
    const int u = swz(tid * 16);  // B unit 4KB: rows 0..63
    pB = bBase + (size_t)(u >> 6) * KCAT + ((u & 63) >> 1);
  }
  const int ldst0 = (tid & ~63) * 16;

  const int abase = swz((wm * 64 + r16) * 64 + kh * 16);
  const int bbase = 8192 + swz((wn * 32 + r16) * 64 + kh * 16);

  auto stage = [&](int buf) {
#pragma unroll
    for (int j = 0; j < 2; ++j)
      gload_lds16(pA[j], ldsB + buf * 12288 + j * 4096 + ldst0);
    gload_lds16(pB, ldsB + buf * 12288 + 8192 + ldst0);
  };

  bf16x8 a[4], b[2];

#define G2_ADV() \
  { pA[0] += 32; pA[1] += 32; pB += 32; }
#define G2_RD(C)                                                              \
  _Pragma("unroll") for (int m = 0; m < 4; ++m)                               \
      a[m] = *(const bf16x8*)(ldsB + (C) * 12288 + abase + m * 1024);         \
  _Pragma("unroll") for (int n = 0; n < 2; ++n)                               \
      b[n] = *(const bf16x8*)(ldsB + (C) * 12288 + bbase + n * 1024);
#define G2_MFMA()                                                             \
  _Pragma("unroll") for (int m = 0; m < 4; ++m)                               \
      _Pragma("unroll") for (int n = 0; n < 2; ++n)                           \
          MFMA16(acc[m][n], a[m], b[n]);
#define G2_STEP(C, N)                                                         \
  {                                                                           \
    G2_RD(C);                                                                 \
    stage(N);                                                                 \
    __builtin_amdgcn_s_setprio(1);                                            \
    G2_MFMA();                                                                \
    __builtin_amdgcn_s_setprio(0);                                            \
    WAITV(3);                                                                 \
    S_BARRIER();                                                              \
    G2_ADV();                                                                 \
  }

  // Prologue: stage t0->b0, t1->b1 (6 out); WAITV(3) -> t0 landed.
  stage(0); IRFENCE();
  G2_ADV();
  stage(1);
  G2_ADV();
  WAITV(3);
  S_BARRIER();

#pragma unroll 1
  for (int it = 0; it < 42; ++it) {  // steps t=0..125, staging t+2 (<=127)
    G2_STEP(0, 2);
    G2_STEP(1, 0);
    G2_STEP(2, 1);
  }
  // Tail: t=126 (b0; drained by t=125's WAITV), t=127 (b1; in flight).
  {
    G2_RD(0);
    G2_MFMA();
    WAITV(0);
    S_BARRIER();
    G2_RD(1);
    G2_MFMA();
  }
#undef G2_STEP
#undef G2_MFMA
#undef G2_RD
#undef G2_ADV

  // Epilogue: plain stores — out = x + 0.5*acc + 0.5*(b2[0]+b2[1]).
#pragma unroll
  for (int m = 0; m < 4; ++m)
#pragma unroll
    for (int n = 0; n < 2; ++n) {
      const int gcol = bcol + wn * 32 + n * 16 + r16;
      const float bb = 0.5f * (b2[gcol] + b2[H_DIM + gcol]);
#pragma unroll
      for (int rr = 0; rr < 4; ++rr) {
        const int grow = brow + wm * 64 + m * 16 + kh * 4 + rr;
        out[(size_t)grow * H_DIM + gcol] =
            x[(size_t)grow * H_DIM + gcol] + 0.5f * acc[m][n][rr] + bb;
      }
    }
}

extern "C" void kernel_launch(void* const* d_in, const int* in_sizes, int n_in,
                              void* d_out, int out_size, void* d_ws, size_t ws_size,
                              hipStream_t stream) {
  const float* x = (const float*)d_in[0];
  const float* scale = (const float*)d_in[1];
  // d_in[2]=gate_kernel, d_in[3]=gate_bias: static routing, logits unused.
  const float* w1 = (const float*)d_in[4];
  const float* b1 = (const float*)d_in[5];
  const float* w2 = (const float*)d_in[6];
  const float* b2 = (const float*)d_in[7];
  float* out = (float*)d_out;

  ushort_t* ws = (ushort_t*)d_ws;
  ushort_t* normed = ws;                                    // [T][H]       8MB
  ushort_t* w1T = normed + (size_t)T_DIM * H_DIM;           // [2][2I][H]  16MB
  ushort_t* w2c = w1T + (size_t)2 * 2 * I_DIM * H_DIM;      // [H][KCAT]    8MB
  ushort_t* actb = w2c + (size_t)H_DIM * KCAT;              // [T][KCAT]   32MB

  // prep1: rmsnorm (4096) + w1 transpose (2048) + w2 transpose->concat (1024)
  k_prep1<<<dim3(T_DIM + 2048 + 1024), 256, 0, stream>>>(
      x, scale, w1, w2, normed, w1T, w2c);
  k_gemm1<<<dim3(1024), 256, 0, stream>>>(normed, w1T, b1, actb);
  k_gemm2<<<dim3(512), 256, 0, stream>>>(actb, w2c, x, b2, out);
}

// Round 17
// 145.757 us; speedup vs baseline: 1.0394x; 1.0174x over previous
//
#include <hip/hip_runtime.h>
#include <hip/hip_bf16.h>
#include <stdint.h>

#define T_DIM 4096
#define H_DIM 1024
#define I_DIM 2048
#define KCAT 4096  // concatenated K for gemm2 (2 experts x I_DIM)

typedef __bf16 bf16x8 __attribute__((ext_vector_type(8)));
typedef float f32x4 __attribute__((ext_vector_type(4)));
typedef unsigned short ushort_t;
typedef unsigned short us4 __attribute__((ext_vector_type(4)));
typedef unsigned short us8 __attribute__((ext_vector_type(8)));

__device__ __forceinline__ unsigned short f32_to_bf16(float f) {
  unsigned int u = __float_as_uint(f);
  u += 0x7fffu + ((u >> 16) & 1u);  // RNE
  return (unsigned short)(u >> 16);
}

__device__ __forceinline__ void gload_lds16(const void* g, void* l) {
  __builtin_amdgcn_global_load_lds(
      (__attribute__((address_space(1))) void*)(uintptr_t)g,
      (__attribute__((address_space(3))) void*)(unsigned int)(uintptr_t)l,
      16, 0, 0);
}

// XOR swizzle (involution; bits 4-6 ^= bits 7-9 of byte offset). Verified R4:
// SQ_LDS_BANK_CONFLICT 6.29M -> 0. Transparent to adds of multiples of 1024.
__device__ __forceinline__ int swz(int L) { return L ^ (((L >> 7) & 7) << 4); }

#define S_BARRIER() asm volatile("s_barrier" ::: "memory")
#define WAITV(n) asm volatile("s_waitcnt vmcnt(" #n ")" ::: "memory")
#define IRFENCE() asm volatile("" ::: "memory")
#define MFMA16(acc, va, vb) \
  acc = __builtin_amdgcn_mfma_f32_16x16x32_bf16(va, vb, acc, 0, 0, 0)

// ------- 64x64 transpose+convert: src f32 (stride sC) -> dst bf16 (stride dR) --
__device__ __forceinline__ void transpose_body64(const float* __restrict__ src,
                                                 ushort_t* __restrict__ dst,
                                                 int sC, int dR, int bx, int by,
                                                 float (*tile)[65]) {
  const int x0 = bx * 64, y0 = by * 64;
  const int tid = threadIdx.x;
  const int lcol4 = tid & 15, lrow = tid >> 4;
#pragma unroll
  for (int i = 0; i < 4; ++i) {
    const int r = lrow + 16 * i;
    const float4 v = ((const float4*)(src + (size_t)(y0 + r) * sC + x0))[lcol4];
    tile[r][lcol4 * 4 + 0] = v.x;
    tile[r][lcol4 * 4 + 1] = v.y;
    tile[r][lcol4 * 4 + 2] = v.z;
    tile[r][lcol4 * 4 + 3] = v.w;
  }
  __syncthreads();
  const int slotr = tid & 7, lcol = tid >> 3;  // 8 row-octs x 32 cols
#pragma unroll
  for (int i = 0; i < 2; ++i) {
    const int c = lcol + 32 * i;
    us8 o;
#pragma unroll
    for (int j = 0; j < 8; ++j) o[j] = f32_to_bf16(tile[slotr * 8 + j][c]);
    *(us8*)(dst + (size_t)(x0 + c) * dR + y0 + slotr * 8) = o;
  }
}

// ------- prep1: rmsnorm (blocks 0..T) + w1T (next 2048) + w2c (next 1024) ------
__global__ __launch_bounds__(256) void k_prep1(
    const float* __restrict__ x, const float* __restrict__ scale,
    const float* __restrict__ w1, const float* __restrict__ w2,
    ushort_t* __restrict__ normed, ushort_t* __restrict__ w1T,
    ushort_t* __restrict__ w2c) {
  __shared__ __align__(16) float shm[64][65];
  const int bid = blockIdx.x;
  if (bid < T_DIM) {
    const int row = bid, tid = threadIdx.x;
    const float4 v = ((const float4*)(x + (size_t)row * H_DIM))[tid];
    float ss = v.x * v.x + v.y * v.y + v.z * v.z + v.w * v.w;
#pragma unroll
    for (int off = 32; off > 0; off >>= 1) ss += __shfl_xor(ss, off);
    if ((tid & 63) == 0) shm[0][tid >> 6] = ss;
    __syncthreads();
    const float tot = shm[0][0] + shm[0][1] + shm[0][2] + shm[0][3];
    const float inv = rsqrtf(tot * (1.0f / H_DIM) + 1e-5f);
    const float4 sc = ((const float4*)scale)[tid];
    us4 o;
    o.x = f32_to_bf16(v.x * inv * sc.x);
    o.y = f32_to_bf16(v.y * inv * sc.y);
    o.z = f32_to_bf16(v.z * inv * sc.z);
    o.w = f32_to_bf16(v.w * inv * sc.w);
    ((us4*)(normed + (size_t)row * H_DIM))[tid] = o;
  } else if (bid < T_DIM + 2048) {
    // w1 [H][2I] -> w1T [2][2I][H]; grid (2I/64=64, H/64=16, 2) flattened.
    const int t = bid - T_DIM;
    const int e = t >> 10;
    transpose_body64(w1 + (size_t)e * H_DIM * 2 * I_DIM,
                     w1T + (size_t)e * 2 * I_DIM * H_DIM, 2 * I_DIM, H_DIM,
                     t & 63, (t >> 6) & 15, shm);
  } else {
    // w2 [I][H] -> w2c [H][KCAT] (expert e at col offset e*I);
    // grid (H/64=16, I/64=32, 2) flattened.
    const int t = bid - T_DIM - 2048;
    const int e = t >> 9;
    transpose_body64(w2 + (size_t)e * I_DIM * H_DIM, w2c + (size_t)e * I_DIM,
                     H_DIM, KCAT, t & 15, (t >> 4) & 31, shm);
  }
}

// ---------------- GEMM1 (R11-verified): 128 x (128g+128l), BK=32 ---------------
// Tri-buffer 72KB, 2 blocks/CU, 4 waves 2x2, WAITV(6)/step, stage 2 ahead.
// Epilogue writes act in the [T][KCAT] expert-concat layout.
__global__ __launch_bounds__(256, 2) void k_gemm1(
    const ushort_t* __restrict__ normed, const ushort_t* __restrict__ w1T,
    const float* __restrict__ b1, ushort_t* __restrict__ act) {
  __shared__ __align__(16) ushort_t lds[3][3][4096];  // 72 KiB
  char* const ldsB = (char*)&lds[0][0][0];
  const int tid = threadIdx.x;
  const int wg = ((blockIdx.x & 7) << 7) + (blockIdx.x >> 3);  // XCD swizzle
  const int e = wg >> 9;
  const int rem = wg & 511;
  const int brow = (rem >> 4) * 128;
  const int bcol = (rem & 15) * 128;
  const int lane = tid & 63;
  const int wid = tid >> 6;
  const int wm = wid >> 1, wn = wid & 1;
  const int r16 = lane & 15, kh = lane >> 4;

  const ushort_t* gBase = w1T + ((size_t)e * 2 * I_DIM + bcol) * H_DIM;
  const ushort_t* lBase = w1T + ((size_t)e * 2 * I_DIM + I_DIM + bcol) * H_DIM;

  f32x4 accg[4][4], accl[4][4];
  const f32x4 zf = {0.f, 0.f, 0.f, 0.f};
#pragma unroll
  for (int m = 0; m < 4; ++m)
#pragma unroll
    for (int n = 0; n < 4; ++n) { accg[m][n] = zf; accl[m][n] = zf; }

  const ushort_t* pA[2];
  const ushort_t* pG[2];
  const ushort_t* pL[2];
#pragma unroll
  for (int j = 0; j < 2; ++j) {
    const int u = swz(j * 4096 + tid * 16);
    const int r = u >> 6, c = (u & 63) >> 1;
    pA[j] = normed + (size_t)(brow + r) * H_DIM + c;
    pG[j] = gBase + (size_t)r * H_DIM + c;
    pL[j] = lBase + (size_t)r * H_DIM + c;
  }
  const int ldst0 = (tid & ~63) * 16;

  const int abase = swz((wm * 64 + r16) * 64 + kh * 16);
  const int bbase = 8192 + swz((wn * 64 + r16) * 64 + kh * 16);

  auto stage = [&](int buf) {
#pragma unroll
    for (int j = 0; j < 2; ++j) {
      gload_lds16(pA[j], ldsB + buf * 24576 + j * 4096 + ldst0);
      gload_lds16(pG[j], ldsB + buf * 24576 + 8192 + j * 4096 + ldst0);
      gload_lds16(pL[j], ldsB + buf * 24576 + 16384 + j * 4096 + ldst0);
    }
  };

  bf16x8 a[4], bg[4], bl[4];

#define G1_ADV()                                                              \
  {                                                                           \
    _Pragma("unroll") for (int j = 0; j < 2; ++j) {                           \
      pA[j] += 32; pG[j] += 32; pL[j] += 32;                                  \
    }                                                                         \
  }
#define G1_RD(C)                                                              \
  _Pragma("unroll") for (int m = 0; m < 4; ++m)                               \
      a[m] = *(const bf16x8*)(ldsB + (C) * 24576 + abase + m * 1024);         \
  _Pragma("unroll") for (int n = 0; n < 4; ++n) {                             \
    bg[n] = *(const bf16x8*)(ldsB + (C) * 24576 + bbase + n * 1024);          \
    bl[n] = *(const bf16x8*)(ldsB + (C) * 24576 + bbase + 8192 + n * 1024);   \
  }
#define G1_MFMA()                                                             \
  _Pragma("unroll") for (int m = 0; m < 4; ++m)                               \
      _Pragma("unroll") for (int n = 0; n < 4; ++n) {                         \
    MFMA16(accg[m][n], a[m], bg[n]);                                          \
    MFMA16(accl[m][n], a[m], bl[n]);                                          \
  }
#define G1_STEP(C, N)                                                         \
  {                                                                           \
    G1_RD(C);                                                                 \
    stage(N);                                                                 \
    __builtin_amdgcn_s_setprio(1);                                            \
    G1_MFMA();                                                                \
    __builtin_amdgcn_s_setprio(0);                                            \
    WAITV(6);                                                                 \
    S_BARRIER();                                                              \
    G1_ADV();                                                                 \
  }

  stage(0); IRFENCE();
  G1_ADV();
  stage(1);
  G1_ADV();
  WAITV(6);
  S_BARRIER();

#pragma unroll 1
  for (int it = 0; it < 10; ++it) {  // steps t=0..29, staging t+2 (<=31)
    G1_STEP(0, 2);
    G1_STEP(1, 0);
    G1_STEP(2, 1);
  }
  // Tail: t=30 (b0; drained by step29's WAITV), t=31 (b1; in flight).
  {
    G1_RD(0);
    G1_MFMA();
    WAITV(0);
    S_BARRIER();
    G1_RD(1);
    G1_MFMA();
  }
#undef G1_STEP
#undef G1_MFMA
#undef G1_RD
#undef G1_ADV

  const float* b1e = b1 + (size_t)e * 2 * I_DIM;
#pragma unroll
  for (int m = 0; m < 4; ++m)
#pragma unroll
    for (int n = 0; n < 4; ++n) {
      const int gcol = bcol + wn * 64 + n * 16 + r16;
      const float bgb = b1e[gcol];
      const float blb = b1e[I_DIM + gcol];
#pragma unroll
      for (int rr = 0; rr < 4; ++rr) {
        const int grow = brow + wm * 64 + m * 16 + kh * 4 + rr;
        const float hg = accg[m][n][rr] + bgb;
        const float hl = accl[m][n][rr] + blb;
        const float g = fminf(hg, 7.f);
        const float l = fminf(fmaxf(hl, -7.f), 7.f);
        const float s = 1.f / (1.f + __expf(-1.702f * g));
        const float av = g * s * (l + 1.f);
        act[(size_t)grow * KCAT + e * I_DIM + gcol] = f32_to_bf16(av);
      }
    }
}

// ---------------- GEMM2: plain GEMM K=4096, 2-wave blocks, wave 64x64 ----------
// out = x + 0.5*(act @ w2c^T) + 0.5*(b2[0]+b2[1]). Tile 128x64, 128 threads
// (2 waves, wm over row-halves), 16 MFMA / 8 ds_reads per wave-step (2:1).
// Tri-buffer 36KB -> 4 blocks/CU. 6 loads/step (A 4 + B 2 chunks of 2KB),
// stage 2 ahead, WAITV(6)/step. 128 K-steps = 42x3 + 2 tail.
__global__ __launch_bounds__(128, 2) void k_gemm2(
    const ushort_t* __restrict__ act, const ushort_t* __restrict__ w2c,
    const float* __restrict__ x, const float* __restrict__ b2,
    float* __restrict__ out) {
  __shared__ __align__(16) ushort_t lds[3][6144];  // 36 KiB: per buf A 8K + B 4K
  char* const ldsB = (char*)&lds[0][0];
  const int tid = threadIdx.x;
  const int wg = ((blockIdx.x & 7) << 6) + (blockIdx.x >> 3);  // XCD swizzle
  const int brow = (wg >> 4) * 128;  // 32 rowtiles
  const int bcol = (wg & 15) * 64;   // 16 coltiles
  const int lane = tid & 63;
  const int wm = tid >> 6;           // 2 waves: row-half
  const int r16 = lane & 15, kh = lane >> 4;

  const ushort_t* aBase = act + (size_t)brow * KCAT;
  const ushort_t* bBase = w2c + (size_t)bcol * KCAT;

  f32x4 acc[4][4];
  const f32x4 zf = {0.f, 0.f, 0.f, 0.f};
#pragma unroll
  for (int m = 0; m < 4; ++m)
#pragma unroll
    for (int n = 0; n < 4; ++n) acc[m][n] = zf;

  // Staging decomposition: A 8KB = 4 chunks of 2KB (128thr x 16B); B 4KB = 2.
  const ushort_t* pA[4];
  const ushort_t* pB[2];
#pragma unroll
  for (int j = 0; j < 4; ++j) {
    const int u = swz(j * 2048 + tid * 16);
    pA[j] = aBase + (size_t)(u >> 6) * KCAT + ((u & 63) >> 1);
  }
#pragma unroll
  for (int j = 0; j < 2; ++j) {
    const int u = swz(j * 2048 + tid * 16);
    pB[j] = bBase + (size_t)(u >> 6) * KCAT + ((u & 63) >> 1);
  }
  const int ldst0 = (tid & ~63) * 16;  // 0 or 1024 within a 2KB chunk

  const int abase = wm * 4096 + swz(r16 * 64 + kh * 16);
  const int bbase = 8192 + swz(r16 * 64 + kh * 16);

  auto stage = [&](int buf) {
#pragma unroll
    for (int j = 0; j < 4; ++j)
      gload_lds16(pA[j], ldsB + buf * 12288 + j * 2048 + ldst0);
#pragma unroll
    for (int j = 0; j < 2; ++j)
      gload_lds16(pB[j], ldsB + buf * 12288 + 8192 + j * 2048 + ldst0);
  };

  bf16x8 a[4], b[4];

#define G2_ADV()                                                              \
  {                                                                           \
    _Pragma("unroll") for (int j = 0; j < 4; ++j) pA[j] += 32;                \
    _Pragma("unroll") for (int j = 0; j < 2; ++j) pB[j] += 32;                \
  }
#define G2_RD(C)                                                              \
  _Pragma("unroll") for (int m = 0; m < 4; ++m)                               \
      a[m] = *(const bf16x8*)(ldsB + (C) * 12288 + abase + m * 1024);         \
  _Pragma("unroll") for (int n = 0; n < 4; ++n)                               \
      b[n] = *(const bf16x8*)(ldsB + (C) * 12288 + bbase + n * 1024);
#define G2_MFMA()                                                             \
  _Pragma("unroll") for (int m = 0; m < 4; ++m)                               \
      _Pragma("unroll") for (int n = 0; n < 4; ++n)                           \
          MFMA16(acc[m][n], a[m], b[n]);
#define G2_STEP(C, N)                                                         \
  {                                                                           \
    G2_RD(C);                                                                 \
    stage(N);                                                                 \
    __builtin_amdgcn_s_setprio(1);                                            \
    G2_MFMA();                                                                \
    __builtin_amdgcn_s_setprio(0);                                            \
    WAITV(6);                                                                 \
    S_BARRIER();                                                              \
    G2_ADV();                                                                 \
  }

  // Prologue: stage t0->b0, t1->b1 (12 out); WAITV(6) -> t0 landed.
  stage(0); IRFENCE();
  G2_ADV();
  stage(1);
  G2_ADV();
  WAITV(6);
  S_BARRIER();

#pragma unroll 1
  for (int it = 0; it < 42; ++it) {  // steps t=0..125, staging t+2 (<=127)
    G2_STEP(0, 2);
    G2_STEP(1, 0);
    G2_STEP(2, 1);
  }
  // Tail: t=126 (b0; drained by t=125's WAITV), t=127 (b1; in flight).
  {
    G2_RD(0);
    G2_MFMA();
    WAITV(0);
    S_BARRIER();
    G2_RD(1);
    G2_MFMA();
  }
#undef G2_STEP
#undef G2_MFMA
#undef G2_RD
#undef G2_ADV

  // Epilogue: plain stores — out = x + 0.5*acc + 0.5*(b2[0]+b2[1]).
#pragma unroll
  for (int m = 0; m < 4; ++m)
#pragma unroll
    for (int n = 0; n < 4; ++n) {
      const int gcol = bcol + n * 16 + r16;
      const float bb = 0.5f * (b2[gcol] + b2[H_DIM + gcol]);
#pragma unroll
      for (int rr = 0; rr < 4; ++rr) {
        const int grow = brow + wm * 64 + m * 16 + kh * 4 + rr;
        out[(size_t)grow * H_DIM + gcol] =
            x[(size_t)grow * H_DIM + gcol] + 0.5f * acc[m][n][rr] + bb;
      }
    }
}

extern "C" void kernel_launch(void* const* d_in, const int* in_sizes, int n_in,
                              void* d_out, int out_size, void* d_ws, size_t ws_size,
                              hipStream_t stream) {
  const float* x = (const float*)d_in[0];
  const float* scale = (const float*)d_in[1];
  // d_in[2]=gate_kernel, d_in[3]=gate_bias: static routing, logits unused.
  const float* w1 = (const float*)d_in[4];
  const float* b1 = (const float*)d_in[5];
  const float* w2 = (const float*)d_in[6];
  const float* b2 = (const float*)d_in[7];
  float* out = (float*)d_out;

  ushort_t* ws = (ushort_t*)d_ws;
  ushort_t* normed = ws;                                    // [T][H]       8MB
  ushort_t* w1T = normed + (size_t)T_DIM * H_DIM;           // [2][2I][H]  16MB
  ushort_t* w2c = w1T + (size_t)2 * 2 * I_DIM * H_DIM;      // [H][KCAT]    8MB
  ushort_t* actb = w2c + (size_t)H_DIM * KCAT;              // [T][KCAT]   32MB

  // prep1: rmsnorm (4096) + w1 transpose (2048) + w2 transpose->concat (1024)
  k_prep1<<<dim3(T_DIM + 2048 + 1024), 256, 0, stream>>>(
      x, scale, w1, w2, normed, w1T, w2c);
  k_gemm1<<<dim3(1024), 256, 0, stream>>>(normed, w1T, b1, actb);
  k_gemm2<<<dim3(512), 128, 0, stream>>>(actb, w2c, x, b2, out);
}